// Round 13
// baseline (232.837 us; speedup 1.0000x reference)
//
#include <hip/hip_runtime.h>

// Problem constants
#define P_TOTAL 132096
#define NPOOL   4096
#define GDIM    1000
#define HDIM    150
#define MGRP    2048
#define KMAX    128

typedef __attribute__((ext_vector_type(4))) float f32x4;
typedef __attribute__((ext_vector_type(2))) float f32x2;
typedef __attribute__((ext_vector_type(4))) unsigned int u32x4;

// ---------- workspace layout (bytes) ----------
// w1c8  fp8 [32][160][32]    163,840 @ 0          (BK=64 K-perm + bank swizzle)
// w1ab8 fp8 [32][320][32]    327,680 @ 163,840    (BK=128 K-perm, pre_gemm)
// w2f8  fp8 [5][160][32]      25,600 @ 491,520    (bank swizzle)
// abpre bf16[4096][320]    2,621,440 @ 517,120
// tabs2 f32 [216][160]       138,240 @ 3,138,560  (dist x genre x spk combos)
// sgrid f32 [2048][128]    1,048,576 @ 3,276,800
// gf8   fp8 [4096][1024]   4,194,304 @ 4,325,376  -> total 8,519,680
#define OFF_W1C8   0
#define OFF_W1AB8  163840
#define OFF_W2F8   491520
#define OFF_ABPRE  517120
#define OFF_TABS2  3138560
#define OFF_SGRID  3276800
#define OFF_GF8    4325376

__device__ __forceinline__ short f2bf(float f) {
  union { float f; unsigned u; } v; v.f = f;
  unsigned r = v.u + 0x7FFFu + ((v.u >> 16) & 1u);   // RNE
  return (short)(r >> 16);
}
__device__ __forceinline__ float bf2f(unsigned short s) {
  return __builtin_bit_cast(float, ((unsigned)s) << 16);
}
__device__ __forceinline__ unsigned char f2fp8(float f) {
  int d = __builtin_amdgcn_cvt_pk_fp8_f32(f, 0.f, 0, false);
  return (unsigned char)(d & 0xFF);
}
__device__ __forceinline__ long mk64(unsigned lo, unsigned hi) {
  return (long)(((unsigned long long)hi << 32) | lo);
}

// 16 fp8 x 16 fp8 -> elementwise product, requantized fp8
__device__ __forceinline__ u32x4 fp8prod16(u32x4 m, u32x4 a) {
  u32x4 r;
  #pragma unroll
  for (int d = 0; d < 4; ++d) {
    f32x2 ml = __builtin_amdgcn_cvt_pk_f32_fp8(m[d], false);
    f32x2 mh = __builtin_amdgcn_cvt_pk_f32_fp8(m[d], true);
    f32x2 al = __builtin_amdgcn_cvt_pk_f32_fp8(a[d], false);
    f32x2 ah = __builtin_amdgcn_cvt_pk_f32_fp8(a[d], true);
    f32x2 pl = ml * al, ph = mh * ah;
    int o = __builtin_amdgcn_cvt_pk_fp8_f32(pl[0], pl[1], 0, false);
    o = __builtin_amdgcn_cvt_pk_fp8_f32(ph[0], ph[1], o, true);
    r[d] = (unsigned)o;
  }
  return r;
}

// ---------- kernel 1: merged prep ----------
#define T1 (32*160*32)          // w1c8
#define T2 (32*320*32)          // w1ab8
#define T3 (5*160*32)           // w2f8
#define TF (NPOOL*256)          // gf8 dwords
#define TT (216*160)            // tabs2 combos
__global__ __launch_bounds__(256) void prep_kernel(
    const float* __restrict__ W1, const float* __restrict__ W2,
    const float* __restrict__ g_i,
    const float* __restrict__ dist_emb, const float* __restrict__ genre_emb,
    const float* __restrict__ spk_emb, const float* __restrict__ b1,
    unsigned char* __restrict__ w1c8, unsigned char* __restrict__ w1ab8,
    unsigned char* __restrict__ w2f8, unsigned* __restrict__ gf8,
    float* __restrict__ tabs2) {
  int idx = blockIdx.x * 256 + threadIdx.x;
  if (idx < T1) {
    // W1c fp8, BK=64 K-perm + bank swizzle: slot g holds quad q = g ^ ((n>>2)&3)
    int c = idx / (160*32); int rem = idx % (160*32);
    int n = rem / 32, kk = rem % 32;
    int s = c >> 1, j = c & 1;
    int g = kk >> 3, i = kk & 7;
    int q = g ^ ((n >> 2) & 3);
    int k = s*64 + q*16 + j*8 + i;
    float v = (k < GDIM && n < HDIM) ? W1[(2000 + k)*HDIM + n] : 0.f;
    w1c8[idx] = f2fp8(v);
  } else if (idx < T1 + T2) {                   // [W1a|W1b] fp8, BK=128 K-perm
    int i = idx - T1;
    int c = i / (320*32); int rem = i % (320*32);
    int n = rem / 32, kk = rem % 32;
    int s = c >> 2, j = c & 3;
    int k = s*128 + (kk >> 3)*32 + j*8 + (kk & 7);
    float v = 0.f;
    if (k < GDIM) {
      if (n < HDIM)                 v = W1[k*HDIM + n];
      else if (n >= 160 && n < 310) v = W1[(1000 + k)*HDIM + (n - 160)];
    }
    w1ab8[i] = f2fp8(v);
  } else if (idx < T1 + T2 + T3) {              // W2 fp8, bank swizzle
    int i = idx - T1 - T2;
    int c = i / (160*32); int rem = i % (160*32);
    int n = rem / 32, kk = rem % 32;
    int g = kk >> 3, ii = kk & 7;
    int q = g ^ ((n >> 2) & 3);
    int k = c*32 + q*8 + ii;
    float v = (k < HDIM && n < HDIM) ? W2[k*HDIM + n] : 0.f;
    w2f8[i] = f2fp8(v);
  } else if (idx < T1 + T2 + T3 + TF) {         // g_i -> fp8 [4096][1024]
    int i = idx - T1 - T2 - T3;
    int row = i >> 8, jd = i & 255;
    int c0 = jd * 4;
    float f0 = (c0     < GDIM) ? g_i[row*GDIM + c0]     : 0.f;
    float f1 = (c0 + 1 < GDIM) ? g_i[row*GDIM + c0 + 1] : 0.f;
    float f2 = (c0 + 2 < GDIM) ? g_i[row*GDIM + c0 + 2] : 0.f;
    float f3 = (c0 + 3 < GDIM) ? g_i[row*GDIM + c0 + 3] : 0.f;
    int d = 0;
    d = __builtin_amdgcn_cvt_pk_fp8_f32(f0, f1, d, false);
    d = __builtin_amdgcn_cvt_pk_fp8_f32(f2, f3, d, true);
    gf8[i] = (unsigned)d;
  } else if (idx < T1 + T2 + T3 + TF + TT) {    // tabs2: combo phi rows (b1 folded)
    int i = idx - T1 - T2 - T3 - TF;
    int row = i / 160, n = i % 160;
    float acc = 0.f;
    if (n < HDIM) {
      int d = row / 24, g = (row / 3) % 8, sp = row % 3;
      acc = b1[n];
      #pragma unroll
      for (int kk = 0; kk < 20; ++kk) {
        acc += dist_emb [d*20 + kk]  * W1[(3000 + kk)*HDIM + n];
        acc += genre_emb[g*20 + kk]  * W1[(3020 + kk)*HDIM + n];
        acc += spk_emb  [sp*20 + kk] * W1[(3040 + kk)*HDIM + n];
      }
    }
    tabs2[i] = acc;
  }
}

// ---------- kernel 2: abpre[4096][320](bf16) = g @ [W1a|W1b], fp8 MFMA ----------
__global__ __launch_bounds__(256) void pre_gemm_kernel(
    const unsigned char* __restrict__ gf8, const unsigned char* __restrict__ w1ab8,
    unsigned short* __restrict__ abpre) {
  int wave = threadIdx.x >> 6, lane = threadIdx.x & 63;
  int quad = lane >> 4, n16 = lane & 15;
  int rowbase = blockIdx.x * 64 + wave * 16;
  int colbase = blockIdx.y * 80;

  f32x4 acc[5];
  #pragma unroll
  for (int t = 0; t < 5; ++t) acc[t] = (f32x4){0.f, 0.f, 0.f, 0.f};

  const unsigned char* arow = gf8 + (long)(rowbase + n16) * 1024 + quad*32;

  for (int s = 0; s < 8; ++s) {
    u32x4 Aa = *(const u32x4*)(arow + s*128);
    u32x4 Ab = *(const u32x4*)(arow + s*128 + 16);
    #pragma unroll
    for (int j = 0; j < 4; ++j) {
      long a = (j == 0) ? mk64(Aa[0], Aa[1]) : (j == 1) ? mk64(Aa[2], Aa[3])
             : (j == 2) ? mk64(Ab[0], Ab[1]) : mk64(Ab[2], Ab[3]);
      const unsigned char* bp = w1ab8 + (((s*4 + j)*320 + colbase + n16) * 32 + quad*8);
      #pragma unroll
      for (int t = 0; t < 5; ++t) {
        long b = *(const long*)(bp + t*16*32);
        acc[t] = __builtin_amdgcn_mfma_f32_16x16x32_fp8_fp8(a, b, acc[t], 0, 0, 0);
      }
    }
  }
  #pragma unroll
  for (int t = 0; t < 5; ++t) {
    #pragma unroll
    for (int r = 0; r < 4; ++r) {
      int row = rowbase + quad*4 + r;
      abpre[(long)row * 320 + colbase + t*16 + n16] = (unsigned short)f2bf(acc[t][r]);
    }
  }
}

// ---------- kernel 3: double-buffered staged MLP, fused gather-product ----------
// block = 128 pairs x 160 cols, 4 waves. K: 16 chunks of 64, ping-pong LDS
// buffers, one barrier/iter; DMA(s+1) hidden under compute(s). Epilogue
// gathers abpre/tabs2 directly (L2-resident). W2 -> dead buf1, h1 -> dead buf0.
__global__ __launch_bounds__(256) void mlp_kernel(
    const unsigned char* __restrict__ gf8,
    const unsigned short* __restrict__ abpre,
    const float* __restrict__ tabs2,
    const unsigned char* __restrict__ w1c8,
    const unsigned char* __restrict__ w2f8,
    const float* __restrict__ ms,
    const float* __restrict__ W3, const float* __restrict__ b2,
    const float* __restrict__ b3,
    const int* __restrict__ mention_ids, const int* __restrict__ antecedent_ids,
    const int* __restrict__ dist_ids, const int* __restrict__ genre_ids,
    const int* __restrict__ spk_ids,
    const int* __restrict__ seg_ids, const int* __restrict__ offs,
    float* __restrict__ sgrid) {

  // buf0 @0, buf1 @26624 (each: Am 8K @0, Aa 8K @8192, B 10K @16384)
  // after K-loop: h1 fp8 4x[32][184] @0 (dead buf0); W2 @26624 (dead buf1)
  __shared__ __align__(16) unsigned char lds[53248];

  int tid = threadIdx.x;
  int wave = tid >> 6, lane = tid & 63;
  int quad = lane >> 4, n16 = lane & 15;
  int gp0 = blockIdx.x * 128;
  int wrow = wave * 32;

  // swizzles (verified r11/r12)
  int jj = (lane & 3) ^ ((lane >> 2) & 3) ^ ((lane >> 4) & 1);
  int srow = lane >> 2;
  int swA = quad ^ (n16 & 3) ^ ((n16 >> 2) & 1);
  int swB = quad ^ ((n16 >> 2) & 3);

  // hoisted gathered A-row pointers (wave owns rounds {w, w+4} x {m,a})
  const unsigned char* pA0 =
      gf8 + (long)mention_ids[gp0 + wave*16 + srow] * 1024 + jj*16;
  const unsigned char* pA1 =
      gf8 + (long)mention_ids[gp0 + (wave + 4)*16 + srow] * 1024 + jj*16;
  const unsigned char* pA2 =
      gf8 + (long)antecedent_ids[gp0 + wave*16 + srow] * 1024 + jj*16;
  const unsigned char* pA3 =
      gf8 + (long)antecedent_ids[gp0 + (wave + 4)*16 + srow] * 1024 + jj*16;
  int dA0 = wave*1024,      dA1 = (wave + 4)*1024;
  int dA2 = 8192 + dA0,     dA3 = 8192 + dA1;

  f32x4 acc0[10], acc1[10];
  #pragma unroll
  for (int t = 0; t < 10; ++t) {
    acc0[t] = (f32x4){0.f, 0.f, 0.f, 0.f};
    acc1[t] = (f32x4){0.f, 0.f, 0.f, 0.f};
  }

  auto issue = [&](int s, int buf) {
    unsigned char* base = lds + buf*26624;
    long so = (long)s * 64;
    __builtin_amdgcn_global_load_lds((const unsigned int*)(pA0 + so),
        (unsigned int*)(base + dA0 + lane*16), 16, 0, 0);
    __builtin_amdgcn_global_load_lds((const unsigned int*)(pA1 + so),
        (unsigned int*)(base + dA1 + lane*16), 16, 0, 0);
    __builtin_amdgcn_global_load_lds((const unsigned int*)(pA2 + so),
        (unsigned int*)(base + dA2 + lane*16), 16, 0, 0);
    __builtin_amdgcn_global_load_lds((const unsigned int*)(pA3 + so),
        (unsigned int*)(base + dA3 + lane*16), 16, 0, 0);
    const unsigned char* wsrc = w1c8 + (long)s*10240;
    __builtin_amdgcn_global_load_lds((const unsigned int*)(wsrc + wave*1024 + (long)lane*16),
        (unsigned int*)(base + 16384 + wave*1024 + lane*16), 16, 0, 0);
    __builtin_amdgcn_global_load_lds((const unsigned int*)(wsrc + (wave+4)*1024 + (long)lane*16),
        (unsigned int*)(base + 16384 + (wave+4)*1024 + lane*16), 16, 0, 0);
    if (wave < 2)
      __builtin_amdgcn_global_load_lds((const unsigned int*)(wsrc + (wave+8)*1024 + (long)lane*16),
          (unsigned int*)(base + 16384 + (wave+8)*1024 + lane*16), 16, 0, 0);
  };

  issue(0, 0);
  for (int s = 0; s < 16; ++s) {
    __syncthreads();
    if (s < 15) issue(s + 1, (s + 1) & 1);
    const unsigned char* cb = lds + (s & 1)*26624;

    u32x4 M0 = *(const u32x4*)(cb + (wrow + n16)*64 + swA*16);
    u32x4 C0 = *(const u32x4*)(cb + 8192 + (wrow + n16)*64 + swA*16);
    u32x4 M1 = *(const u32x4*)(cb + (wrow + 16 + n16)*64 + swA*16);
    u32x4 C1 = *(const u32x4*)(cb + 8192 + (wrow + 16 + n16)*64 + swA*16);
    u32x4 P0 = fp8prod16(M0, C0);
    u32x4 P1 = fp8prod16(M1, C1);

    #pragma unroll
    for (int j = 0; j < 2; ++j) {
      long a0 = (j == 0) ? mk64(P0[0], P0[1]) : mk64(P0[2], P0[3]);
      long a1 = (j == 0) ? mk64(P1[0], P1[1]) : mk64(P1[2], P1[3]);
      const unsigned char* bp = cb + 16384 + j*5120 + n16*32 + swB*8;
      #pragma unroll
      for (int t = 0; t < 10; ++t) {
        long b = *(const long*)(bp + t*512);
        acc0[t] = __builtin_amdgcn_mfma_f32_16x16x32_fp8_fp8(a0, b, acc0[t], 0, 0, 0);
        acc1[t] = __builtin_amdgcn_mfma_f32_16x16x32_fp8_fp8(a1, b, acc1[t], 0, 0, 0);
      }
    }
  }
  __syncthreads();

  // stage W2 into dead buf1 (overlaps epilogue below)
  for (int r = wave; r < 25; r += 4) {
    __builtin_amdgcn_global_load_lds(
        (const unsigned int*)(w2f8 + r*1024 + (long)lane*16),
        (unsigned int*)(lds + 26624 + r*1024), 16, 0, 0);
  }

  // ---- epilogue 1 (per tile to bound VGPR): gather bias, relu, h1->fp8 ----
  unsigned char* h1w = lds + wave * 5888;   // [32][184] fp8
  #pragma unroll
  for (int tile = 0; tile < 2; ++tile) {
    int idm[4], ida[4], itab[4];
    #pragma unroll
    for (int r = 0; r < 4; ++r) {
      int gp = gp0 + wrow + tile*16 + quad*4 + r;
      idm[r]  = mention_ids[gp];
      ida[r]  = antecedent_ids[gp];
      itab[r] = dist_ids[gp]*24 + genre_ids[gp]*3 + spk_ids[gp];
    }
    f32x4* acc = tile ? acc1 : acc0;
    #pragma unroll
    for (int t = 0; t < 10; ++t) {
      int n = t*16 + n16;
      #pragma unroll
      for (int r = 0; r < 4; ++r) {
        float v = acc[t][r]
                + bf2f(abpre[(long)idm[r]*320 + n])
                + bf2f(abpre[(long)ida[r]*320 + 160 + n])
                + tabs2[itab[r]*160 + n];
        h1w[(tile*16 + quad*4 + r)*184 + n] = f2fp8(fmaxf(v, 0.f));
      }
    }
  }
  __syncthreads();                      // W2 DMA drained + h1 visible

  // ---- layer 2 (fp8 MFMA, all LDS) + layer 3 ----
  float bias3 = b3[0];
  float w3v[10], b2v[10];
  #pragma unroll
  for (int t = 0; t < 10; ++t) {
    int n = t*16 + n16;
    w3v[t] = (n < HDIM) ? W3[n] : 0.f;
    b2v[t] = (n < HDIM) ? b2[n] : 0.f;
  }

  #pragma unroll
  for (int tile = 0; tile < 2; ++tile) {
    f32x4 acc2[10];
    #pragma unroll
    for (int t = 0; t < 10; ++t) acc2[t] = (f32x4){0.f, 0.f, 0.f, 0.f};

    #pragma unroll
    for (int c = 0; c < 5; ++c) {
      long a = *(const long*)(h1w + (tile*16 + n16)*184 + c*32 + quad*8);
      const unsigned char* bp = lds + 26624 + (c*160 + n16)*32 + swB*8;
      #pragma unroll
      for (int t = 0; t < 10; ++t) {
        long b = *(const long*)(bp + t*512);
        acc2[t] = __builtin_amdgcn_mfma_f32_16x16x32_fp8_fp8(a, b, acc2[t], 0, 0, 0);
      }
    }

    float part[4] = {0.f, 0.f, 0.f, 0.f};
    #pragma unroll
    for (int t = 0; t < 10; ++t) {
      #pragma unroll
      for (int r = 0; r < 4; ++r) {
        float h2 = fmaxf(acc2[t][r] + b2v[t], 0.f);
        part[r] += h2 * w3v[t];
      }
    }
    for (int msk = 1; msk < 16; msk <<= 1) {
      #pragma unroll
      for (int r = 0; r < 4; ++r) part[r] += __shfl_xor(part[r], msk);
    }

    if (n16 == 0) {
      #pragma unroll
      for (int r = 0; r < 4; ++r) {
        int gp = gp0 + wrow + tile*16 + quad*4 + r;
        float sc = part[r] + bias3 + ms[mention_ids[gp]] + ms[antecedent_ids[gp]];
        sgrid[seg_ids[gp] * KMAX + offs[gp]] = sc;
      }
    }
  }
}

// ---------- kernel 4: per-group softmax (+epsilon) and full output fill ----------
__global__ __launch_bounds__(128) void softmax_kernel(const float* __restrict__ sgrid,
                                                      const int* __restrict__ lengths,
                                                      float* __restrict__ out) {
  int b = blockIdx.x, t = threadIdx.x;
  if (b == 0) {
    out[t] = (t == 0) ? 1.0f : 1000.0f;
    if (t == 0) out[128] = 1000.0f;
    return;
  }
  int m = b - 1;
  int len = lengths[m];
  float s = (t < len) ? sgrid[m * KMAX + t] : -1e30f;

  __shared__ float redA[2];
  __shared__ float redB[2];

  float v = s;
  #pragma unroll
  for (int o = 32; o >= 1; o >>= 1) v = fmaxf(v, __shfl_xor(v, o));
  if ((t & 63) == 0) redA[t >> 6] = v;
  __syncthreads();
  float mx = fmaxf(fmaxf(redA[0], redA[1]), 0.0f);

  float e = (t < len) ? expf(s - mx) : 0.f;
  float sum = e;
  #pragma unroll
  for (int o = 32; o >= 1; o >>= 1) sum += __shfl_xor(sum, o);
  if ((t & 63) == 0) redB[t >> 6] = sum;
  __syncthreads();

  float eps_e = expf(-mx);
  float denom = redB[0] + redB[1] + eps_e;

  float* row = out + (long)(m + 1) * 129;
  float val;
  if (t < len)       val = e / denom;
  else if (t == len) val = eps_e / denom;
  else               val = 1000.0f;
  row[t] = val;
  if (t == 0) row[128] = (len == KMAX) ? (eps_e / denom) : 1000.0f;
}

extern "C" void kernel_launch(void* const* d_in, const int* in_sizes, int n_in,
                              void* d_out, int out_size, void* d_ws, size_t ws_size,
                              hipStream_t stream) {
  const float* g_i        = (const float*)d_in[0];
  const float* ms         = (const float*)d_in[1];
  const float* dist_emb   = (const float*)d_in[2];
  const float* genre_emb  = (const float*)d_in[3];
  const float* spk_emb    = (const float*)d_in[4];
  const float* W1         = (const float*)d_in[5];
  const float* b1         = (const float*)d_in[6];
  const float* W2         = (const float*)d_in[7];
  const float* b2         = (const float*)d_in[8];
  const float* W3         = (const float*)d_in[9];
  const float* b3         = (const float*)d_in[10];
  const int* mention_ids    = (const int*)d_in[11];
  const int* antecedent_ids = (const int*)d_in[12];
  const int* dist_ids       = (const int*)d_in[13];
  const int* genre_ids      = (const int*)d_in[14];
  const int* spk_ids        = (const int*)d_in[15];
  const int* lengths        = (const int*)d_in[16];
  const int* seg_ids        = (const int*)d_in[17];
  const int* offsets        = (const int*)d_in[18];

  char* ws = (char*)d_ws;
  unsigned char* w1c8  = (unsigned char*)(ws + OFF_W1C8);
  unsigned char* w1ab8 = (unsigned char*)(ws + OFF_W1AB8);
  unsigned char* w2f8  = (unsigned char*)(ws + OFF_W2F8);
  unsigned short* abpre = (unsigned short*)(ws + OFF_ABPRE);
  float* tabs2  = (float*)(ws + OFF_TABS2);
  float* sgrid  = (float*)(ws + OFF_SGRID);
  unsigned char* gf8  = (unsigned char*)(ws + OFF_GF8);

  const int prepN = T1 + T2 + T3 + TF + TT;
  prep_kernel<<<(prepN + 255)/256, 256, 0, stream>>>(W1, W2, g_i,
                                                     dist_emb, genre_emb, spk_emb, b1,
                                                     w1c8, w1ab8, w2f8,
                                                     (unsigned*)gf8, tabs2);
  dim3 gpre(NPOOL/64, 4);
  pre_gemm_kernel<<<gpre, 256, 0, stream>>>(gf8, w1ab8, abpre);
  mlp_kernel<<<P_TOTAL/128, 256, 0, stream>>>(gf8, abpre, tabs2, w1c8, w2f8, ms,
                                              W3, b2, b3,
                                              mention_ids, antecedent_ids,
                                              dist_ids, genre_ids, spk_ids,
                                              seg_ids, offsets, sgrid);
  softmax_kernel<<<MGRP + 1, 128, 0, stream>>>(sgrid, lengths, (float*)d_out);
}

// Round 14
// 212.895 us; speedup vs baseline: 1.0937x; 1.0937x over previous
//
#include <hip/hip_runtime.h>

// Problem constants
#define P_TOTAL 132096
#define NPOOL   4096
#define GDIM    1000
#define HDIM    150
#define MGRP    2048
#define KMAX    128

typedef __attribute__((ext_vector_type(4))) float f32x4;
typedef __attribute__((ext_vector_type(2))) float f32x2;
typedef __attribute__((ext_vector_type(4))) unsigned int u32x4;

// ---------- workspace layout (bytes) ----------
#define OFF_W1C8   0
#define OFF_W1AB8  163840
#define OFF_W2F8   491520
#define OFF_ABPRE  517120
#define OFF_TABS   3138560
#define OFF_SGRID  3151360
#define OFF_GF8    4200448
#define OFF_EXTRAS 8394752

__device__ __forceinline__ short f2bf(float f) {
  union { float f; unsigned u; } v; v.f = f;
  unsigned r = v.u + 0x7FFFu + ((v.u >> 16) & 1u);   // RNE
  return (short)(r >> 16);
}
__device__ __forceinline__ float bf2f(unsigned short s) {
  return __builtin_bit_cast(float, ((unsigned)s) << 16);
}
__device__ __forceinline__ unsigned char f2fp8(float f) {
  int d = __builtin_amdgcn_cvt_pk_fp8_f32(f, 0.f, 0, false);
  return (unsigned char)(d & 0xFF);
}
__device__ __forceinline__ long mk64(unsigned lo, unsigned hi) {
  return (long)(((unsigned long long)hi << 32) | lo);
}

// 16 fp8 x 16 fp8 -> elementwise product, requantized fp8
__device__ __forceinline__ u32x4 fp8prod16(u32x4 m, u32x4 a) {
  u32x4 r;
  #pragma unroll
  for (int d = 0; d < 4; ++d) {
    f32x2 ml = __builtin_amdgcn_cvt_pk_f32_fp8(m[d], false);
    f32x2 mh = __builtin_amdgcn_cvt_pk_f32_fp8(m[d], true);
    f32x2 al = __builtin_amdgcn_cvt_pk_f32_fp8(a[d], false);
    f32x2 ah = __builtin_amdgcn_cvt_pk_f32_fp8(a[d], true);
    f32x2 pl = ml * al, ph = mh * ah;
    int o = __builtin_amdgcn_cvt_pk_fp8_f32(pl[0], pl[1], 0, false);
    o = __builtin_amdgcn_cvt_pk_fp8_f32(ph[0], ph[1], o, true);
    r[d] = (unsigned)o;
  }
  return r;
}

// ---------- kernel 1: merged prep (coalesced weight packs) ----------
// S1: w1c8, thread per (c,n), kk-loop      5,120
// S2: w1ab8, thread per (c,n)             10,240
// S3: w2f8, thread per (c,n)                 800
// S4: gf8 dwords                       1,048,576
// S5: tabs 20x160                          3,200
#define S1 5120
#define S2 10240
#define S3 800
#define S4 (NPOOL*256)
#define S5 (20*160)
__global__ __launch_bounds__(256) void prep_kernel(
    const float* __restrict__ W1, const float* __restrict__ W2,
    const float* __restrict__ g_i,
    const float* __restrict__ dist_emb, const float* __restrict__ genre_emb,
    const float* __restrict__ spk_emb, const float* __restrict__ b1,
    unsigned char* __restrict__ w1c8, unsigned char* __restrict__ w1ab8,
    unsigned char* __restrict__ w2f8, unsigned* __restrict__ gf8,
    float* __restrict__ tabs) {
  int idx = blockIdx.x * 256 + threadIdx.x;
  if (idx < S1) {                               // w1c8 [c][n][kk], coalesced-in-n reads
    int c = idx / 160, n = idx % 160;
    int s = c >> 1, j = c & 1;
    unsigned dw[8];
    #pragma unroll
    for (int d = 0; d < 8; ++d) {
      unsigned acc = 0;
      #pragma unroll
      for (int b = 0; b < 4; ++b) {
        int kk = d*4 + b;
        int g = kk >> 3, i = kk & 7;
        int q = g ^ ((n >> 2) & 3);             // bank swizzle baked
        int k = s*64 + q*16 + j*8 + i;
        float v = (k < GDIM && n < HDIM) ? W1[(2000 + k)*HDIM + n] : 0.f;
        acc |= ((unsigned)f2fp8(v)) << (8*b);
      }
      dw[d] = acc;
    }
    u32x4 lo = {dw[0], dw[1], dw[2], dw[3]};
    u32x4 hi = {dw[4], dw[5], dw[6], dw[7]};
    *(u32x4*)(w1c8 + c*5120 + n*32)      = lo;
    *(u32x4*)(w1c8 + c*5120 + n*32 + 16) = hi;
  } else if (idx < S1 + S2) {                   // w1ab8 [c][n][kk], BK=128 K-perm
    int i2 = idx - S1;
    int c = i2 / 320, n = i2 % 320;
    int s = c >> 2, j = c & 3;
    unsigned dw[8];
    #pragma unroll
    for (int d = 0; d < 8; ++d) {
      unsigned acc = 0;
      #pragma unroll
      for (int b = 0; b < 4; ++b) {
        int kk = d*4 + b;
        int g = kk >> 3, i = kk & 7;
        int k = s*128 + g*32 + j*8 + i;
        float v = 0.f;
        if (k < GDIM) {
          if (n < HDIM)                 v = W1[k*HDIM + n];
          else if (n >= 160 && n < 310) v = W1[(1000 + k)*HDIM + (n - 160)];
        }
        acc |= ((unsigned)f2fp8(v)) << (8*b);
      }
      dw[d] = acc;
    }
    u32x4 lo = {dw[0], dw[1], dw[2], dw[3]};
    u32x4 hi = {dw[4], dw[5], dw[6], dw[7]};
    *(u32x4*)(w1ab8 + c*10240 + n*32)      = lo;
    *(u32x4*)(w1ab8 + c*10240 + n*32 + 16) = hi;
  } else if (idx < S1 + S2 + S3) {              // w2f8 [c][n][kk], bank swizzle
    int i2 = idx - S1 - S2;
    int c = i2 / 160, n = i2 % 160;
    unsigned dw[8];
    #pragma unroll
    for (int d = 0; d < 8; ++d) {
      unsigned acc = 0;
      #pragma unroll
      for (int b = 0; b < 4; ++b) {
        int kk = d*4 + b;
        int g = kk >> 3, ii = kk & 7;
        int q = g ^ ((n >> 2) & 3);
        int k = c*32 + q*8 + ii;
        float v = (k < HDIM && n < HDIM) ? W2[k*HDIM + n] : 0.f;
        acc |= ((unsigned)f2fp8(v)) << (8*b);
      }
      dw[d] = acc;
    }
    u32x4 lo = {dw[0], dw[1], dw[2], dw[3]};
    u32x4 hi = {dw[4], dw[5], dw[6], dw[7]};
    *(u32x4*)(w2f8 + c*5120 + n*32)      = lo;
    *(u32x4*)(w2f8 + c*5120 + n*32 + 16) = hi;
  } else if (idx < S1 + S2 + S3 + S4) {         // g_i -> fp8 [4096][1024]
    int i = idx - S1 - S2 - S3;
    int row = i >> 8, jd = i & 255;
    int c0 = jd * 4;
    float f0 = (c0     < GDIM) ? g_i[row*GDIM + c0]     : 0.f;
    float f1 = (c0 + 1 < GDIM) ? g_i[row*GDIM + c0 + 1] : 0.f;
    float f2 = (c0 + 2 < GDIM) ? g_i[row*GDIM + c0 + 2] : 0.f;
    float f3 = (c0 + 3 < GDIM) ? g_i[row*GDIM + c0 + 3] : 0.f;
    int d = 0;
    d = __builtin_amdgcn_cvt_pk_fp8_f32(f0, f1, d, false);
    d = __builtin_amdgcn_cvt_pk_fp8_f32(f2, f3, d, true);
    gf8[i] = (unsigned)d;
  } else if (idx < S1 + S2 + S3 + S4 + S5) {    // phi tables (b1 folded)
    int i = idx - S1 - S2 - S3 - S4;
    int row = i / 160, n = i % 160;
    float acc = 0.f;
    if (n < HDIM) {
      const float* emb; int woff;
      if (row < 9)       { emb = dist_emb  + row*20;      woff = 3000; acc = b1[n]; }
      else if (row < 17) { emb = genre_emb + (row-9)*20;  woff = 3020; }
      else               { emb = spk_emb   + (row-17)*20; woff = 3040; }
      #pragma unroll
      for (int kk = 0; kk < 20; ++kk) acc += emb[kk] * W1[(woff + kk)*HDIM + n];
    }
    tabs[i] = acc;
  }
}

// ---------- kernel 2: abpre[4096][320](bf16) = g @ [W1a|W1b], fp8 MFMA ----------
__global__ __launch_bounds__(256) void pre_gemm_kernel(
    const unsigned char* __restrict__ gf8, const unsigned char* __restrict__ w1ab8,
    unsigned short* __restrict__ abpre) {
  int wave = threadIdx.x >> 6, lane = threadIdx.x & 63;
  int quad = lane >> 4, n16 = lane & 15;
  int rowbase = blockIdx.x * 64 + wave * 16;
  int colbase = blockIdx.y * 80;

  f32x4 acc[5];
  #pragma unroll
  for (int t = 0; t < 5; ++t) acc[t] = (f32x4){0.f, 0.f, 0.f, 0.f};

  const unsigned char* arow = gf8 + (long)(rowbase + n16) * 1024 + quad*32;

  for (int s = 0; s < 8; ++s) {
    u32x4 Aa = *(const u32x4*)(arow + s*128);
    u32x4 Ab = *(const u32x4*)(arow + s*128 + 16);
    #pragma unroll
    for (int j = 0; j < 4; ++j) {
      long a = (j == 0) ? mk64(Aa[0], Aa[1]) : (j == 1) ? mk64(Aa[2], Aa[3])
             : (j == 2) ? mk64(Ab[0], Ab[1]) : mk64(Ab[2], Ab[3]);
      const unsigned char* bp = w1ab8 + (((s*4 + j)*320 + colbase + n16) * 32 + quad*8);
      #pragma unroll
      for (int t = 0; t < 5; ++t) {
        long b = *(const long*)(bp + t*16*32);
        acc[t] = __builtin_amdgcn_mfma_f32_16x16x32_fp8_fp8(a, b, acc[t], 0, 0, 0);
      }
    }
  }
  #pragma unroll
  for (int t = 0; t < 5; ++t) {
    #pragma unroll
    for (int r = 0; r < 4; ++r) {
      int row = rowbase + quad*4 + r;
      abpre[(long)row * 320 + colbase + t*16 + n16] = (unsigned short)f2bf(acc[t][r]);
    }
  }
}

// ---------- kernel 3: per-pair bias rows (latency-tolerant) ----------
__global__ __launch_bounds__(256) void extras_kernel(
    const unsigned short* __restrict__ abpre, const float* __restrict__ tabs,
    const int* __restrict__ mid, const int* __restrict__ aid,
    const int* __restrict__ did, const int* __restrict__ gid,
    const int* __restrict__ sid,
    unsigned short* __restrict__ extras, int pbase) {
  int t = threadIdx.x;
  int lp = blockIdx.x * 8 + (t >> 5);
  int p = pbase + lp;
  int l = t & 31;
  int m = mid[p], a = aid[p];
  const float* Dd = tabs + did[p]*160;
  const float* Ge = tabs + (9 + gid[p])*160;
  const float* Se = tabs + (17 + sid[p])*160;
  #pragma unroll
  for (int j = 0; j < 5; ++j) {
    int n = l + j*32;
    float v = bf2f(abpre[(long)m*320 + n]) + bf2f(abpre[(long)a*320 + 160 + n])
            + Dd[n] + Ge[n] + Se[n];
    extras[(long)lp*160 + n] = (unsigned short)f2bf(v);
  }
}

// ---------- kernel 4: double-buffered staged MLP with fused gather-product ----
// (r12 structure, verbatim: 79 us, VGPR 116)
__global__ __launch_bounds__(256) void mlp_kernel(
    const unsigned char* __restrict__ gf8,
    const unsigned short* __restrict__ extras,
    const unsigned char* __restrict__ w1c8,
    const unsigned char* __restrict__ w2f8,
    const float* __restrict__ ms,
    const float* __restrict__ W3, const float* __restrict__ b2,
    const float* __restrict__ b3,
    const int* __restrict__ mention_ids, const int* __restrict__ antecedent_ids,
    const int* __restrict__ seg_ids, const int* __restrict__ offs,
    float* __restrict__ sgrid, int pbase) {

  __shared__ __align__(16) unsigned char lds[53248];

  int tid = threadIdx.x;
  int wave = tid >> 6, lane = tid & 63;
  int quad = lane >> 4, n16 = lane & 15;
  int lp0 = blockIdx.x * 128;
  int gp0 = pbase + lp0;
  int wrow = wave * 32;

  int jj = (lane & 3) ^ ((lane >> 2) & 3) ^ ((lane >> 4) & 1);
  int srow = lane >> 2;
  int swA = quad ^ (n16 & 3) ^ ((n16 >> 2) & 1);
  int swB = quad ^ ((n16 >> 2) & 3);

  const unsigned char* pA0 =
      gf8 + (long)mention_ids[gp0 + wave*16 + srow] * 1024 + jj*16;
  const unsigned char* pA1 =
      gf8 + (long)mention_ids[gp0 + (wave + 4)*16 + srow] * 1024 + jj*16;
  const unsigned char* pA2 =
      gf8 + (long)antecedent_ids[gp0 + wave*16 + srow] * 1024 + jj*16;
  const unsigned char* pA3 =
      gf8 + (long)antecedent_ids[gp0 + (wave + 4)*16 + srow] * 1024 + jj*16;
  int dA0 = wave*1024,      dA1 = (wave + 4)*1024;
  int dA2 = 8192 + dA0,     dA3 = 8192 + dA1;

  f32x4 acc0[10], acc1[10];
  #pragma unroll
  for (int t = 0; t < 10; ++t) {
    acc0[t] = (f32x4){0.f, 0.f, 0.f, 0.f};
    acc1[t] = (f32x4){0.f, 0.f, 0.f, 0.f};
  }

  auto issue = [&](int s, int buf) {
    unsigned char* base = lds + buf*26624;
    long so = (long)s * 64;
    __builtin_amdgcn_global_load_lds((const unsigned int*)(pA0 + so),
        (unsigned int*)(base + dA0 + lane*16), 16, 0, 0);
    __builtin_amdgcn_global_load_lds((const unsigned int*)(pA1 + so),
        (unsigned int*)(base + dA1 + lane*16), 16, 0, 0);
    __builtin_amdgcn_global_load_lds((const unsigned int*)(pA2 + so),
        (unsigned int*)(base + dA2 + lane*16), 16, 0, 0);
    __builtin_amdgcn_global_load_lds((const unsigned int*)(pA3 + so),
        (unsigned int*)(base + dA3 + lane*16), 16, 0, 0);
    const unsigned char* wsrc = w1c8 + (long)s*10240;
    __builtin_amdgcn_global_load_lds((const unsigned int*)(wsrc + wave*1024 + (long)lane*16),
        (unsigned int*)(base + 16384 + wave*1024 + lane*16), 16, 0, 0);
    __builtin_amdgcn_global_load_lds((const unsigned int*)(wsrc + (wave+4)*1024 + (long)lane*16),
        (unsigned int*)(base + 16384 + (wave+4)*1024 + lane*16), 16, 0, 0);
    if (wave < 2)
      __builtin_amdgcn_global_load_lds((const unsigned int*)(wsrc + (wave+8)*1024 + (long)lane*16),
          (unsigned int*)(base + 16384 + (wave+8)*1024 + lane*16), 16, 0, 0);
  };

  issue(0, 0);
  for (int s = 0; s < 16; ++s) {
    __syncthreads();
    if (s < 15) issue(s + 1, (s + 1) & 1);
    const unsigned char* cb = lds + (s & 1)*26624;

    u32x4 M0 = *(const u32x4*)(cb + (wrow + n16)*64 + swA*16);
    u32x4 C0 = *(const u32x4*)(cb + 8192 + (wrow + n16)*64 + swA*16);
    u32x4 M1 = *(const u32x4*)(cb + (wrow + 16 + n16)*64 + swA*16);
    u32x4 C1 = *(const u32x4*)(cb + 8192 + (wrow + 16 + n16)*64 + swA*16);
    u32x4 P0 = fp8prod16(M0, C0);
    u32x4 P1 = fp8prod16(M1, C1);

    #pragma unroll
    for (int j = 0; j < 2; ++j) {
      long a0 = (j == 0) ? mk64(P0[0], P0[1]) : mk64(P0[2], P0[3]);
      long a1 = (j == 0) ? mk64(P1[0], P1[1]) : mk64(P1[2], P1[3]);
      const unsigned char* bp = cb + 16384 + j*5120 + n16*32 + swB*8;
      #pragma unroll
      for (int t = 0; t < 10; ++t) {
        long b = *(const long*)(bp + t*512);
        acc0[t] = __builtin_amdgcn_mfma_f32_16x16x32_fp8_fp8(a0, b, acc0[t], 0, 0, 0);
        acc1[t] = __builtin_amdgcn_mfma_f32_16x16x32_fp8_fp8(a1, b, acc1[t], 0, 0, 0);
      }
    }
  }
  __syncthreads();

  for (int r = wave; r < 25; r += 4) {
    __builtin_amdgcn_global_load_lds(
        (const unsigned int*)(w2f8 + r*1024 + (long)lane*16),
        (unsigned int*)(lds + 26624 + r*1024), 16, 0, 0);
  }

  unsigned char* h1w = lds + wave * 5888;   // [32][184] fp8
  #pragma unroll
  for (int t = 0; t < 10; ++t) {
    int n = t*16 + n16;
    #pragma unroll
    for (int r = 0; r < 4; ++r) {
      int row0 = quad*4 + r;
      float v0 = acc0[t][r] + bf2f(extras[(long)(lp0 + wrow + row0)*160 + n]);
      float v1 = acc1[t][r] + bf2f(extras[(long)(lp0 + wrow + 16 + row0)*160 + n]);
      h1w[row0*184 + n]        = f2fp8(fmaxf(v0, 0.f));
      h1w[(16 + row0)*184 + n] = f2fp8(fmaxf(v1, 0.f));
    }
  }
  __syncthreads();

  float bias3 = b3[0];
  float w3v[10], b2v[10];
  #pragma unroll
  for (int t = 0; t < 10; ++t) {
    int n = t*16 + n16;
    w3v[t] = (n < HDIM) ? W3[n] : 0.f;
    b2v[t] = (n < HDIM) ? b2[n] : 0.f;
  }

  #pragma unroll
  for (int tile = 0; tile < 2; ++tile) {
    f32x4 acc2[10];
    #pragma unroll
    for (int t = 0; t < 10; ++t) acc2[t] = (f32x4){0.f, 0.f, 0.f, 0.f};

    #pragma unroll
    for (int c = 0; c < 5; ++c) {
      long a = *(const long*)(h1w + (tile*16 + n16)*184 + c*32 + quad*8);
      const unsigned char* bp = lds + 26624 + (c*160 + n16)*32 + swB*8;
      #pragma unroll
      for (int t = 0; t < 10; ++t) {
        long b = *(const long*)(bp + t*512);
        acc2[t] = __builtin_amdgcn_mfma_f32_16x16x32_fp8_fp8(a, b, acc2[t], 0, 0, 0);
      }
    }

    float part[4] = {0.f, 0.f, 0.f, 0.f};
    #pragma unroll
    for (int t = 0; t < 10; ++t) {
      #pragma unroll
      for (int r = 0; r < 4; ++r) {
        float h2 = fmaxf(acc2[t][r] + b2v[t], 0.f);
        part[r] += h2 * w3v[t];
      }
    }
    for (int msk = 1; msk < 16; msk <<= 1) {
      #pragma unroll
      for (int r = 0; r < 4; ++r) part[r] += __shfl_xor(part[r], msk);
    }

    if (n16 == 0) {
      #pragma unroll
      for (int r = 0; r < 4; ++r) {
        int gp = gp0 + wrow + tile*16 + quad*4 + r;
        float sc = part[r] + bias3 + ms[mention_ids[gp]] + ms[antecedent_ids[gp]];
        sgrid[seg_ids[gp] * KMAX + offs[gp]] = sc;
      }
    }
  }
}

// ---------- kernel 5: per-group softmax (+epsilon) and full output fill ----------
__global__ __launch_bounds__(128) void softmax_kernel(const float* __restrict__ sgrid,
                                                      const int* __restrict__ lengths,
                                                      float* __restrict__ out) {
  int b = blockIdx.x, t = threadIdx.x;
  if (b == 0) {
    out[t] = (t == 0) ? 1.0f : 1000.0f;
    if (t == 0) out[128] = 1000.0f;
    return;
  }
  int m = b - 1;
  int len = lengths[m];
  float s = (t < len) ? sgrid[m * KMAX + t] : -1e30f;

  __shared__ float redA[2];
  __shared__ float redB[2];

  float v = s;
  #pragma unroll
  for (int o = 32; o >= 1; o >>= 1) v = fmaxf(v, __shfl_xor(v, o));
  if ((t & 63) == 0) redA[t >> 6] = v;
  __syncthreads();
  float mx = fmaxf(fmaxf(redA[0], redA[1]), 0.0f);

  float e = (t < len) ? expf(s - mx) : 0.f;
  float sum = e;
  #pragma unroll
  for (int o = 32; o >= 1; o >>= 1) sum += __shfl_xor(sum, o);
  if ((t & 63) == 0) redB[t >> 6] = sum;
  __syncthreads();

  float eps_e = expf(-mx);
  float denom = redB[0] + redB[1] + eps_e;

  float* row = out + (long)(m + 1) * 129;
  float val;
  if (t < len)       val = e / denom;
  else if (t == len) val = eps_e / denom;
  else               val = 1000.0f;
  row[t] = val;
  if (t == 0) row[128] = (len == KMAX) ? (eps_e / denom) : 1000.0f;
}

extern "C" void kernel_launch(void* const* d_in, const int* in_sizes, int n_in,
                              void* d_out, int out_size, void* d_ws, size_t ws_size,
                              hipStream_t stream) {
  const float* g_i        = (const float*)d_in[0];
  const float* ms         = (const float*)d_in[1];
  const float* dist_emb   = (const float*)d_in[2];
  const float* genre_emb  = (const float*)d_in[3];
  const float* spk_emb    = (const float*)d_in[4];
  const float* W1         = (const float*)d_in[5];
  const float* b1         = (const float*)d_in[6];
  const float* W2         = (const float*)d_in[7];
  const float* b2         = (const float*)d_in[8];
  const float* W3         = (const float*)d_in[9];
  const float* b3         = (const float*)d_in[10];
  const int* mention_ids    = (const int*)d_in[11];
  const int* antecedent_ids = (const int*)d_in[12];
  const int* dist_ids       = (const int*)d_in[13];
  const int* genre_ids      = (const int*)d_in[14];
  const int* spk_ids        = (const int*)d_in[15];
  const int* lengths        = (const int*)d_in[16];
  const int* seg_ids        = (const int*)d_in[17];
  const int* offsets        = (const int*)d_in[18];

  char* ws = (char*)d_ws;
  unsigned char* w1c8  = (unsigned char*)(ws + OFF_W1C8);
  unsigned char* w1ab8 = (unsigned char*)(ws + OFF_W1AB8);
  unsigned char* w2f8  = (unsigned char*)(ws + OFF_W2F8);
  unsigned short* abpre = (unsigned short*)(ws + OFF_ABPRE);
  float* tabs   = (float*)(ws + OFF_TABS);
  float* sgrid  = (float*)(ws + OFF_SGRID);
  unsigned char* gf8  = (unsigned char*)(ws + OFF_GF8);
  unsigned short* extras = (unsigned short*)(ws + OFF_EXTRAS);

  // extras chunking from scratch budget (constant per process -> capture-safe)
  size_t avail = (ws_size > OFF_EXTRAS) ? ws_size - OFF_EXTRAS : 0;
  int nchunk;
  if      (avail >= (size_t)P_TOTAL * 320)      nchunk = 1;
  else if (avail >= (size_t)P_TOTAL * 160)      nchunk = 2;
  else if (avail >= (size_t)P_TOTAL * 80)       nchunk = 4;
  else                                          nchunk = 8;
  int npc = P_TOTAL / nchunk;

  const int prepN = S1 + S2 + S3 + S4 + S5;
  prep_kernel<<<(prepN + 255)/256, 256, 0, stream>>>(W1, W2, g_i,
                                                     dist_emb, genre_emb, spk_emb, b1,
                                                     w1c8, w1ab8, w2f8,
                                                     (unsigned*)gf8, tabs);
  dim3 gpre(NPOOL/64, 4);
  pre_gemm_kernel<<<gpre, 256, 0, stream>>>(gf8, w1ab8, abpre);
  for (int c = 0; c < nchunk; ++c) {
    int pbase = c * npc;
    extras_kernel<<<npc/8, 256, 0, stream>>>(abpre, tabs,
                                             mention_ids, antecedent_ids,
                                             dist_ids, genre_ids, spk_ids,
                                             extras, pbase);
    mlp_kernel<<<npc/128, 256, 0, stream>>>(gf8, extras, w1c8, w2f8, ms,
                                            W3, b2, b3,
                                            mention_ids, antecedent_ids,
                                            seg_ids, offsets, sgrid, pbase);
  }
  softmax_kernel<<<MGRP + 1, 128, 0, stream>>>(sgrid, lengths, (float*)d_out);
}

// Round 15
// 204.006 us; speedup vs baseline: 1.1413x; 1.0436x over previous
//
#include <hip/hip_runtime.h>

// Problem constants
#define P_TOTAL 132096
#define NPOOL   4096
#define GDIM    1000
#define HDIM    150
#define MGRP    2048
#define KMAX    128

typedef __attribute__((ext_vector_type(4))) float f32x4;
typedef __attribute__((ext_vector_type(2))) float f32x2;
typedef __attribute__((ext_vector_type(4))) unsigned int u32x4;

// ---------- workspace layout (bytes) ----------
// w1c8  fp8 [32][160][32]    163,840 @ 0          (BK=64 K-perm + bank swizzle)
// w1ab8 fp8 [32][320][32]    327,680 @ 163,840    (BK=128 K-perm, pre_gemm)
// w2f8  fp8 [5][160][32]      25,600 @ 491,520    (bank swizzle)
// abpre bf16[4096][320]    2,621,440 @ 517,120
// tabs2 f32 [216][160]       138,240 @ 3,138,560  (dist x genre x spk combos)
// sgrid f32 [2048][128]    1,048,576 @ 3,276,800
// gf8   fp8 [4096][1024]   4,194,304 @ 4,325,376
// extras bf16[npc][160]              @ 8,519,680
#define OFF_W1C8   0
#define OFF_W1AB8  163840
#define OFF_W2F8   491520
#define OFF_ABPRE  517120
#define OFF_TABS2  3138560
#define OFF_SGRID  3276800
#define OFF_GF8    4325376
#define OFF_EXTRAS 8519680

__device__ __forceinline__ short f2bf(float f) {
  union { float f; unsigned u; } v; v.f = f;
  unsigned r = v.u + 0x7FFFu + ((v.u >> 16) & 1u);   // RNE
  return (short)(r >> 16);
}
__device__ __forceinline__ float bf2f(unsigned short s) {
  return __builtin_bit_cast(float, ((unsigned)s) << 16);
}
__device__ __forceinline__ unsigned char f2fp8(float f) {
  int d = __builtin_amdgcn_cvt_pk_fp8_f32(f, 0.f, 0, false);
  return (unsigned char)(d & 0xFF);
}
__device__ __forceinline__ long mk64(unsigned lo, unsigned hi) {
  return (long)(((unsigned long long)hi << 32) | lo);
}

// 16 fp8 x 16 fp8 -> elementwise product, requantized fp8
__device__ __forceinline__ u32x4 fp8prod16(u32x4 m, u32x4 a) {
  u32x4 r;
  #pragma unroll
  for (int d = 0; d < 4; ++d) {
    f32x2 ml = __builtin_amdgcn_cvt_pk_f32_fp8(m[d], false);
    f32x2 mh = __builtin_amdgcn_cvt_pk_f32_fp8(m[d], true);
    f32x2 al = __builtin_amdgcn_cvt_pk_f32_fp8(a[d], false);
    f32x2 ah = __builtin_amdgcn_cvt_pk_f32_fp8(a[d], true);
    f32x2 pl = ml * al, ph = mh * ah;
    int o = __builtin_amdgcn_cvt_pk_fp8_f32(pl[0], pl[1], 0, false);
    o = __builtin_amdgcn_cvt_pk_fp8_f32(ph[0], ph[1], o, true);
    r[d] = (unsigned)o;
  }
  return r;
}

// ---------- kernel 1: merged prep ----------
#define S1 5120
#define S2 10240
#define S3 800
#define S4 (NPOOL*256)
#define S5 (216*160)
__global__ __launch_bounds__(256) void prep_kernel(
    const float* __restrict__ W1, const float* __restrict__ W2,
    const float* __restrict__ g_i,
    const float* __restrict__ dist_emb, const float* __restrict__ genre_emb,
    const float* __restrict__ spk_emb, const float* __restrict__ b1,
    unsigned char* __restrict__ w1c8, unsigned char* __restrict__ w1ab8,
    unsigned char* __restrict__ w2f8, unsigned* __restrict__ gf8,
    float* __restrict__ tabs2) {
  int idx = blockIdx.x * 256 + threadIdx.x;
  if (idx < S1) {                               // w1c8 [c][n][kk], coalesced-in-n reads
    int c = idx / 160, n = idx % 160;
    int s = c >> 1, j = c & 1;
    unsigned dw[8];
    #pragma unroll
    for (int d = 0; d < 8; ++d) {
      unsigned acc = 0;
      #pragma unroll
      for (int b = 0; b < 4; ++b) {
        int kk = d*4 + b;
        int g = kk >> 3, i = kk & 7;
        int q = g ^ ((n >> 2) & 3);             // bank swizzle baked
        int k = s*64 + q*16 + j*8 + i;
        float v = (k < GDIM && n < HDIM) ? W1[(2000 + k)*HDIM + n] : 0.f;
        acc |= ((unsigned)f2fp8(v)) << (8*b);
      }
      dw[d] = acc;
    }
    u32x4 lo = {dw[0], dw[1], dw[2], dw[3]};
    u32x4 hi = {dw[4], dw[5], dw[6], dw[7]};
    *(u32x4*)(w1c8 + c*5120 + n*32)      = lo;
    *(u32x4*)(w1c8 + c*5120 + n*32 + 16) = hi;
  } else if (idx < S1 + S2) {                   // w1ab8 [c][n][kk], BK=128 K-perm
    int i2 = idx - S1;
    int c = i2 / 320, n = i2 % 320;
    int s = c >> 2, j = c & 3;
    unsigned dw[8];
    #pragma unroll
    for (int d = 0; d < 8; ++d) {
      unsigned acc = 0;
      #pragma unroll
      for (int b = 0; b < 4; ++b) {
        int kk = d*4 + b;
        int g = kk >> 3, i = kk & 7;
        int k = s*128 + g*32 + j*8 + i;
        float v = 0.f;
        if (k < GDIM) {
          if (n < HDIM)                 v = W1[k*HDIM + n];
          else if (n >= 160 && n < 310) v = W1[(1000 + k)*HDIM + (n - 160)];
        }
        acc |= ((unsigned)f2fp8(v)) << (8*b);
      }
      dw[d] = acc;
    }
    u32x4 lo = {dw[0], dw[1], dw[2], dw[3]};
    u32x4 hi = {dw[4], dw[5], dw[6], dw[7]};
    *(u32x4*)(w1ab8 + c*10240 + n*32)      = lo;
    *(u32x4*)(w1ab8 + c*10240 + n*32 + 16) = hi;
  } else if (idx < S1 + S2 + S3) {              // w2f8 [c][n][kk], bank swizzle
    int i2 = idx - S1 - S2;
    int c = i2 / 160, n = i2 % 160;
    unsigned dw[8];
    #pragma unroll
    for (int d = 0; d < 8; ++d) {
      unsigned acc = 0;
      #pragma unroll
      for (int b = 0; b < 4; ++b) {
        int kk = d*4 + b;
        int g = kk >> 3, ii = kk & 7;
        int q = g ^ ((n >> 2) & 3);
        int k = c*32 + q*8 + ii;
        float v = (k < HDIM && n < HDIM) ? W2[k*HDIM + n] : 0.f;
        acc |= ((unsigned)f2fp8(v)) << (8*b);
      }
      dw[d] = acc;
    }
    u32x4 lo = {dw[0], dw[1], dw[2], dw[3]};
    u32x4 hi = {dw[4], dw[5], dw[6], dw[7]};
    *(u32x4*)(w2f8 + c*5120 + n*32)      = lo;
    *(u32x4*)(w2f8 + c*5120 + n*32 + 16) = hi;
  } else if (idx < S1 + S2 + S3 + S4) {         // g_i -> fp8 [4096][1024]
    int i = idx - S1 - S2 - S3;
    int row = i >> 8, jd = i & 255;
    int c0 = jd * 4;
    float f0 = (c0     < GDIM) ? g_i[row*GDIM + c0]     : 0.f;
    float f1 = (c0 + 1 < GDIM) ? g_i[row*GDIM + c0 + 1] : 0.f;
    float f2 = (c0 + 2 < GDIM) ? g_i[row*GDIM + c0 + 2] : 0.f;
    float f3 = (c0 + 3 < GDIM) ? g_i[row*GDIM + c0 + 3] : 0.f;
    int d = 0;
    d = __builtin_amdgcn_cvt_pk_fp8_f32(f0, f1, d, false);
    d = __builtin_amdgcn_cvt_pk_fp8_f32(f2, f3, d, true);
    gf8[i] = (unsigned)d;
  } else if (idx < S1 + S2 + S3 + S4 + S5) {    // tabs2: combo phi rows (b1 folded)
    int i = idx - S1 - S2 - S3 - S4;
    int row = i / 160, n = i % 160;
    float acc = 0.f;
    if (n < HDIM) {
      int d = row / 24, g = (row / 3) % 8, sp = row % 3;
      acc = b1[n];
      #pragma unroll
      for (int kk = 0; kk < 20; ++kk) {
        acc += dist_emb [d*20 + kk]  * W1[(3000 + kk)*HDIM + n];
        acc += genre_emb[g*20 + kk]  * W1[(3020 + kk)*HDIM + n];
        acc += spk_emb  [sp*20 + kk] * W1[(3040 + kk)*HDIM + n];
      }
    }
    tabs2[i] = acc;
  }
}

// ---------- kernel 2: abpre[4096][320](bf16) = g @ [W1a|W1b], fp8 MFMA ----------
// grid (128, 4): 32 rows x 2 waves, 80 cols per y -> 512 blocks (2/CU)
__global__ __launch_bounds__(128) void pre_gemm_kernel(
    const unsigned char* __restrict__ gf8, const unsigned char* __restrict__ w1ab8,
    unsigned short* __restrict__ abpre) {
  int wave = threadIdx.x >> 6, lane = threadIdx.x & 63;
  int quad = lane >> 4, n16 = lane & 15;
  int rowbase = blockIdx.x * 32 + wave * 16;
  int colbase = blockIdx.y * 80;

  f32x4 acc[5];
  #pragma unroll
  for (int t = 0; t < 5; ++t) acc[t] = (f32x4){0.f, 0.f, 0.f, 0.f};

  const unsigned char* arow = gf8 + (long)(rowbase + n16) * 1024 + quad*32;

  for (int s = 0; s < 8; ++s) {
    u32x4 Aa = *(const u32x4*)(arow + s*128);
    u32x4 Ab = *(const u32x4*)(arow + s*128 + 16);
    #pragma unroll
    for (int j = 0; j < 4; ++j) {
      long a = (j == 0) ? mk64(Aa[0], Aa[1]) : (j == 1) ? mk64(Aa[2], Aa[3])
             : (j == 2) ? mk64(Ab[0], Ab[1]) : mk64(Ab[2], Ab[3]);
      const unsigned char* bp = w1ab8 + (((s*4 + j)*320 + colbase + n16) * 32 + quad*8);
      #pragma unroll
      for (int t = 0; t < 5; ++t) {
        long b = *(const long*)(bp + t*16*32);
        acc[t] = __builtin_amdgcn_mfma_f32_16x16x32_fp8_fp8(a, b, acc[t], 0, 0, 0);
      }
    }
  }
  #pragma unroll
  for (int t = 0; t < 5; ++t) {
    #pragma unroll
    for (int r = 0; r < 4; ++r) {
      int row = rowbase + quad*4 + r;
      abpre[(long)row * 320 + colbase + t*16 + n16] = (unsigned short)f2bf(acc[t][r]);
    }
  }
}

// ---------- kernel 3: per-pair bias rows (vectorized, 16 lanes/pair) ----------
// extras[p] = abpre_m[m] + abpre_a[a] + tabs2[combo]   (bf16 x160, u32 I/O)
__global__ __launch_bounds__(256) void extras_kernel(
    const unsigned* __restrict__ abpre32, const float* __restrict__ tabs2,
    const int* __restrict__ mid, const int* __restrict__ aid,
    const int* __restrict__ did, const int* __restrict__ gid,
    const int* __restrict__ sid,
    unsigned* __restrict__ extras32, int pbase) {
  int t = threadIdx.x;
  int lp = blockIdx.x * 16 + (t >> 4);
  int p = pbase + lp;
  int l = t & 15;
  int m = mid[p], a = aid[p];
  int itab = did[p]*24 + gid[p]*3 + sid[p];
  const unsigned* pm = abpre32 + (long)m*160;        // m-part: dwords 0..79
  const unsigned* pa = abpre32 + (long)a*160 + 80;   // a-part: dwords 80..159
  const f32x2* tb = (const f32x2*)(tabs2 + (long)itab*160);
  #pragma unroll
  for (int j = 0; j < 5; ++j) {
    int d = l + j*16;
    unsigned um = pm[d], ua = pa[d];
    f32x2 tt = tb[d];
    float v0 = bf2f((unsigned short)(um & 0xffff)) + bf2f((unsigned short)(ua & 0xffff)) + tt[0];
    float v1 = bf2f((unsigned short)(um >> 16))    + bf2f((unsigned short)(ua >> 16))    + tt[1];
    unsigned o = ((unsigned)(unsigned short)f2bf(v0))
               | (((unsigned)(unsigned short)f2bf(v1)) << 16);
    extras32[(long)lp*80 + d] = o;
  }
}

// ---------- kernel 4: double-buffered staged MLP with fused gather-product ----
// (r12 structure, verbatim: 79 us, VGPR 116)
__global__ __launch_bounds__(256) void mlp_kernel(
    const unsigned char* __restrict__ gf8,
    const unsigned short* __restrict__ extras,
    const unsigned char* __restrict__ w1c8,
    const unsigned char* __restrict__ w2f8,
    const float* __restrict__ ms,
    const float* __restrict__ W3, const float* __restrict__ b2,
    const float* __restrict__ b3,
    const int* __restrict__ mention_ids, const int* __restrict__ antecedent_ids,
    const int* __restrict__ seg_ids, const int* __restrict__ offs,
    float* __restrict__ sgrid, int pbase) {

  __shared__ __align__(16) unsigned char lds[53248];

  int tid = threadIdx.x;
  int wave = tid >> 6, lane = tid & 63;
  int quad = lane >> 4, n16 = lane & 15;
  int lp0 = blockIdx.x * 128;
  int gp0 = pbase + lp0;
  int wrow = wave * 32;

  int jj = (lane & 3) ^ ((lane >> 2) & 3) ^ ((lane >> 4) & 1);
  int srow = lane >> 2;
  int swA = quad ^ (n16 & 3) ^ ((n16 >> 2) & 1);
  int swB = quad ^ ((n16 >> 2) & 3);

  const unsigned char* pA0 =
      gf8 + (long)mention_ids[gp0 + wave*16 + srow] * 1024 + jj*16;
  const unsigned char* pA1 =
      gf8 + (long)mention_ids[gp0 + (wave + 4)*16 + srow] * 1024 + jj*16;
  const unsigned char* pA2 =
      gf8 + (long)antecedent_ids[gp0 + wave*16 + srow] * 1024 + jj*16;
  const unsigned char* pA3 =
      gf8 + (long)antecedent_ids[gp0 + (wave + 4)*16 + srow] * 1024 + jj*16;
  int dA0 = wave*1024,      dA1 = (wave + 4)*1024;
  int dA2 = 8192 + dA0,     dA3 = 8192 + dA1;

  f32x4 acc0[10], acc1[10];
  #pragma unroll
  for (int t = 0; t < 10; ++t) {
    acc0[t] = (f32x4){0.f, 0.f, 0.f, 0.f};
    acc1[t] = (f32x4){0.f, 0.f, 0.f, 0.f};
  }

  auto issue = [&](int s, int buf) {
    unsigned char* base = lds + buf*26624;
    long so = (long)s * 64;
    __builtin_amdgcn_global_load_lds((const unsigned int*)(pA0 + so),
        (unsigned int*)(base + dA0 + lane*16), 16, 0, 0);
    __builtin_amdgcn_global_load_lds((const unsigned int*)(pA1 + so),
        (unsigned int*)(base + dA1 + lane*16), 16, 0, 0);
    __builtin_amdgcn_global_load_lds((const unsigned int*)(pA2 + so),
        (unsigned int*)(base + dA2 + lane*16), 16, 0, 0);
    __builtin_amdgcn_global_load_lds((const unsigned int*)(pA3 + so),
        (unsigned int*)(base + dA3 + lane*16), 16, 0, 0);
    const unsigned char* wsrc = w1c8 + (long)s*10240;
    __builtin_amdgcn_global_load_lds((const unsigned int*)(wsrc + wave*1024 + (long)lane*16),
        (unsigned int*)(base + 16384 + wave*1024 + lane*16), 16, 0, 0);
    __builtin_amdgcn_global_load_lds((const unsigned int*)(wsrc + (wave+4)*1024 + (long)lane*16),
        (unsigned int*)(base + 16384 + (wave+4)*1024 + lane*16), 16, 0, 0);
    if (wave < 2)
      __builtin_amdgcn_global_load_lds((const unsigned int*)(wsrc + (wave+8)*1024 + (long)lane*16),
          (unsigned int*)(base + 16384 + (wave+8)*1024 + lane*16), 16, 0, 0);
  };

  issue(0, 0);
  for (int s = 0; s < 16; ++s) {
    __syncthreads();
    if (s < 15) issue(s + 1, (s + 1) & 1);
    const unsigned char* cb = lds + (s & 1)*26624;

    u32x4 M0 = *(const u32x4*)(cb + (wrow + n16)*64 + swA*16);
    u32x4 C0 = *(const u32x4*)(cb + 8192 + (wrow + n16)*64 + swA*16);
    u32x4 M1 = *(const u32x4*)(cb + (wrow + 16 + n16)*64 + swA*16);
    u32x4 C1 = *(const u32x4*)(cb + 8192 + (wrow + 16 + n16)*64 + swA*16);
    u32x4 P0 = fp8prod16(M0, C0);
    u32x4 P1 = fp8prod16(M1, C1);

    #pragma unroll
    for (int j = 0; j < 2; ++j) {
      long a0 = (j == 0) ? mk64(P0[0], P0[1]) : mk64(P0[2], P0[3]);
      long a1 = (j == 0) ? mk64(P1[0], P1[1]) : mk64(P1[2], P1[3]);
      const unsigned char* bp = cb + 16384 + j*5120 + n16*32 + swB*8;
      #pragma unroll
      for (int t = 0; t < 10; ++t) {
        long b = *(const long*)(bp + t*512);
        acc0[t] = __builtin_amdgcn_mfma_f32_16x16x32_fp8_fp8(a0, b, acc0[t], 0, 0, 0);
        acc1[t] = __builtin_amdgcn_mfma_f32_16x16x32_fp8_fp8(a1, b, acc1[t], 0, 0, 0);
      }
    }
  }
  __syncthreads();

  for (int r = wave; r < 25; r += 4) {
    __builtin_amdgcn_global_load_lds(
        (const unsigned int*)(w2f8 + r*1024 + (long)lane*16),
        (unsigned int*)(lds + 26624 + r*1024), 16, 0, 0);
  }

  unsigned char* h1w = lds + wave * 5888;   // [32][184] fp8
  #pragma unroll
  for (int t = 0; t < 10; ++t) {
    int n = t*16 + n16;
    #pragma unroll
    for (int r = 0; r < 4; ++r) {
      int row0 = quad*4 + r;
      float v0 = acc0[t][r] + bf2f(extras[(long)(lp0 + wrow + row0)*160 + n]);
      float v1 = acc1[t][r] + bf2f(extras[(long)(lp0 + wrow + 16 + row0)*160 + n]);
      h1w[row0*184 + n]        = f2fp8(fmaxf(v0, 0.f));
      h1w[(16 + row0)*184 + n] = f2fp8(fmaxf(v1, 0.f));
    }
  }
  __syncthreads();

  float bias3 = b3[0];
  float w3v[10], b2v[10];
  #pragma unroll
  for (int t = 0; t < 10; ++t) {
    int n = t*16 + n16;
    w3v[t] = (n < HDIM) ? W3[n] : 0.f;
    b2v[t] = (n < HDIM) ? b2[n] : 0.f;
  }

  #pragma unroll
  for (int tile = 0; tile < 2; ++tile) {
    f32x4 acc2[10];
    #pragma unroll
    for (int t = 0; t < 10; ++t) acc2[t] = (f32x4){0.f, 0.f, 0.f, 0.f};

    #pragma unroll
    for (int c = 0; c < 5; ++c) {
      long a = *(const long*)(h1w + (tile*16 + n16)*184 + c*32 + quad*8);
      const unsigned char* bp = lds + 26624 + (c*160 + n16)*32 + swB*8;
      #pragma unroll
      for (int t = 0; t < 10; ++t) {
        long b = *(const long*)(bp + t*512);
        acc2[t] = __builtin_amdgcn_mfma_f32_16x16x32_fp8_fp8(a, b, acc2[t], 0, 0, 0);
      }
    }

    float part[4] = {0.f, 0.f, 0.f, 0.f};
    #pragma unroll
    for (int t = 0; t < 10; ++t) {
      #pragma unroll
      for (int r = 0; r < 4; ++r) {
        float h2 = fmaxf(acc2[t][r] + b2v[t], 0.f);
        part[r] += h2 * w3v[t];
      }
    }
    for (int msk = 1; msk < 16; msk <<= 1) {
      #pragma unroll
      for (int r = 0; r < 4; ++r) part[r] += __shfl_xor(part[r], msk);
    }

    if (n16 == 0) {
      #pragma unroll
      for (int r = 0; r < 4; ++r) {
        int gp = gp0 + wrow + tile*16 + quad*4 + r;
        float sc = part[r] + bias3 + ms[mention_ids[gp]] + ms[antecedent_ids[gp]];
        sgrid[seg_ids[gp] * KMAX + offs[gp]] = sc;
      }
    }
  }
}

// ---------- kernel 5: per-group softmax (+epsilon) and full output fill ----------
__global__ __launch_bounds__(128) void softmax_kernel(const float* __restrict__ sgrid,
                                                      const int* __restrict__ lengths,
                                                      float* __restrict__ out) {
  int b = blockIdx.x, t = threadIdx.x;
  if (b == 0) {
    out[t] = (t == 0) ? 1.0f : 1000.0f;
    if (t == 0) out[128] = 1000.0f;
    return;
  }
  int m = b - 1;
  int len = lengths[m];
  float s = (t < len) ? sgrid[m * KMAX + t] : -1e30f;

  __shared__ float redA[2];
  __shared__ float redB[2];

  float v = s;
  #pragma unroll
  for (int o = 32; o >= 1; o >>= 1) v = fmaxf(v, __shfl_xor(v, o));
  if ((t & 63) == 0) redA[t >> 6] = v;
  __syncthreads();
  float mx = fmaxf(fmaxf(redA[0], redA[1]), 0.0f);

  float e = (t < len) ? expf(s - mx) : 0.f;
  float sum = e;
  #pragma unroll
  for (int o = 32; o >= 1; o >>= 1) sum += __shfl_xor(sum, o);
  if ((t & 63) == 0) redB[t >> 6] = sum;
  __syncthreads();

  float eps_e = expf(-mx);
  float denom = redB[0] + redB[1] + eps_e;

  float* row = out + (long)(m + 1) * 129;
  float val;
  if (t < len)       val = e / denom;
  else if (t == len) val = eps_e / denom;
  else               val = 1000.0f;
  row[t] = val;
  if (t == 0) row[128] = (len == KMAX) ? (eps_e / denom) : 1000.0f;
}

extern "C" void kernel_launch(void* const* d_in, const int* in_sizes, int n_in,
                              void* d_out, int out_size, void* d_ws, size_t ws_size,
                              hipStream_t stream) {
  const float* g_i        = (const float*)d_in[0];
  const float* ms         = (const float*)d_in[1];
  const float* dist_emb   = (const float*)d_in[2];
  const float* genre_emb  = (const float*)d_in[3];
  const float* spk_emb    = (const float*)d_in[4];
  const float* W1         = (const float*)d_in[5];
  const float* b1         = (const float*)d_in[6];
  const float* W2         = (const float*)d_in[7];
  const float* b2         = (const float*)d_in[8];
  const float* W3         = (const float*)d_in[9];
  const float* b3         = (const float*)d_in[10];
  const int* mention_ids    = (const int*)d_in[11];
  const int* antecedent_ids = (const int*)d_in[12];
  const int* dist_ids       = (const int*)d_in[13];
  const int* genre_ids      = (const int*)d_in[14];
  const int* spk_ids        = (const int*)d_in[15];
  const int* lengths        = (const int*)d_in[16];
  const int* seg_ids        = (const int*)d_in[17];
  const int* offsets        = (const int*)d_in[18];

  char* ws = (char*)d_ws;
  unsigned char* w1c8  = (unsigned char*)(ws + OFF_W1C8);
  unsigned char* w1ab8 = (unsigned char*)(ws + OFF_W1AB8);
  unsigned char* w2f8  = (unsigned char*)(ws + OFF_W2F8);
  unsigned short* abpre = (unsigned short*)(ws + OFF_ABPRE);
  float* tabs2  = (float*)(ws + OFF_TABS2);
  float* sgrid  = (float*)(ws + OFF_SGRID);
  unsigned char* gf8  = (unsigned char*)(ws + OFF_GF8);
  unsigned short* extras = (unsigned short*)(ws + OFF_EXTRAS);

  // extras chunking from scratch budget (constant per process -> capture-safe)
  size_t avail = (ws_size > OFF_EXTRAS) ? ws_size - OFF_EXTRAS : 0;
  int nchunk;
  if      (avail >= (size_t)P_TOTAL * 320)      nchunk = 1;
  else if (avail >= (size_t)P_TOTAL * 160)      nchunk = 2;
  else if (avail >= (size_t)P_TOTAL * 80)       nchunk = 4;
  else                                          nchunk = 8;
  int npc = P_TOTAL / nchunk;

  const int prepN = S1 + S2 + S3 + S4 + S5;
  prep_kernel<<<(prepN + 255)/256, 256, 0, stream>>>(W1, W2, g_i,
                                                     dist_emb, genre_emb, spk_emb, b1,
                                                     w1c8, w1ab8, w2f8,
                                                     (unsigned*)gf8, tabs2);
  dim3 gpre(NPOOL/32, 4);
  pre_gemm_kernel<<<gpre, 128, 0, stream>>>(gf8, w1ab8, abpre);
  for (int c = 0; c < nchunk; ++c) {
    int pbase = c * npc;
    extras_kernel<<<npc/16, 256, 0, stream>>>((const unsigned*)abpre, tabs2,
                                              mention_ids, antecedent_ids,
                                              dist_ids, genre_ids, spk_ids,
                                              (unsigned*)extras, pbase);
    mlp_kernel<<<npc/128, 256, 0, stream>>>(gf8, extras, w1c8, w2f8, ms,
                                            W3, b2, b3,
                                            mention_ids, antecedent_ids,
                                            seg_ids, offsets, sgrid, pbase);
  }
  softmax_kernel<<<MGRP + 1, 128, 0, stream>>>(sgrid, lengths, (float*)d_out);
}